// Round 2
// baseline (460.889 us; speedup 1.0000x reference)
//
#include <hip/hip_runtime.h>
#include <stdint.h>

typedef __attribute__((ext_vector_type(8))) short short8;
typedef __attribute__((ext_vector_type(4))) float f32x4;

#define AS1 __attribute__((address_space(1)))
#define AS3 __attribute__((address_space(3)))

__device__ __forceinline__ void gload_lds16(const void* g, void* l) {
  __builtin_amdgcn_global_load_lds((const AS1 void*)g, (AS3 void*)l, 16, 0, 0);
}

__device__ __forceinline__ short f2bf(float f) {
  uint32_t u = __float_as_uint(f);
  u += 0x7fffu + ((u >> 16) & 1u);
  return (short)(u >> 16);
}

// ---------------- fp32 -> bf16 conversion, 8 elems/thread ----------------
__global__ __launch_bounds__(256) void cvt_bf16(const float* __restrict__ in,
                                                short* __restrict__ out, int n8) {
  int i = blockIdx.x * 256 + threadIdx.x;
  if (i >= n8) return;
  const float4* p = (const float4*)(in + (size_t)i * 8);
  float4 a = p[0], b = p[1];
  short8 o;
  o[0] = f2bf(a.x); o[1] = f2bf(a.y); o[2] = f2bf(a.z); o[3] = f2bf(a.w);
  o[4] = f2bf(b.x); o[5] = f2bf(b.y); o[6] = f2bf(b.z); o[7] = f2bf(b.w);
  *(short8*)(out + (size_t)i * 8) = o;
}

// ---------------- GEMM: C[M,N] = A[M,K] * B[N,K]^T (both bf16, K%64==0) ----
// epi==0: scatter to q/k/v [B=4][H=16][S=2048][64] bf16  (N=3072, M=8192)
// epi==1: plain fp32 row-major [M,N] store
__global__ __launch_bounds__(256) void gemm_bt(const short* __restrict__ A,
                                               const short* __restrict__ B,
                                               int K, int epi,
                                               short* __restrict__ q,
                                               short* __restrict__ k,
                                               short* __restrict__ v,
                                               float* __restrict__ outF, int N) {
  __shared__ short Al[128 * 64];
  __shared__ short Bl[128 * 64];
  const int tid = threadIdx.x;
  const int lane = tid & 63;
  const int wv = tid >> 6;
  const int wr = wv >> 1, wc = wv & 1;
  const int bm = blockIdx.y * 128, bn = blockIdx.x * 128;
  const int l15 = lane & 15, l4 = lane >> 4;

  f32x4 acc[4][4] = {};

  for (int kt = 0; kt < K; kt += 64) {
    // 128 rows x 64 cols x 2B = 16 KB per tile = 1024 x 16B chunks -> 4 iters x 256 thr
#pragma unroll
    for (int i = 0; i < 4; ++i) {
      int c = i * 256 + tid;
      int row = c >> 3, col = (c & 7) * 8;
      gload_lds16(A + (size_t)(bm + row) * K + kt + col, (char*)Al + (size_t)c * 16);
      gload_lds16(B + (size_t)(bn + row) * K + kt + col, (char*)Bl + (size_t)c * 16);
    }
    __syncthreads();
#pragma unroll
    for (int ks = 0; ks < 2; ++ks) {
      short8 af[4], bf[4];
#pragma unroll
      for (int mf = 0; mf < 4; ++mf)
        af[mf] = *(const short8*)&Al[(wr * 64 + mf * 16 + l15) * 64 + ks * 32 + l4 * 8];
#pragma unroll
      for (int nf = 0; nf < 4; ++nf)
        bf[nf] = *(const short8*)&Bl[(wc * 64 + nf * 16 + l15) * 64 + ks * 32 + l4 * 8];
#pragma unroll
      for (int mf = 0; mf < 4; ++mf)
#pragma unroll
        for (int nf = 0; nf < 4; ++nf)
          acc[mf][nf] =
              __builtin_amdgcn_mfma_f32_16x16x32_bf16(af[mf], bf[nf], acc[mf][nf], 0, 0, 0);
    }
    __syncthreads();
  }

  if (epi == 0) {
#pragma unroll
    for (int mf = 0; mf < 4; ++mf)
#pragma unroll
      for (int r = 0; r < 4; ++r) {
        int m = bm + wr * 64 + mf * 16 + l4 * 4 + r;
        int bb = m >> 11, s = m & 2047;
#pragma unroll
        for (int nf = 0; nf < 4; ++nf) {
          int n = bn + wc * 64 + nf * 16 + l15;
          int which = n >> 10, d = n & 1023, h = d >> 6, dh = d & 63;
          short* dst = (which == 0) ? q : ((which == 1) ? k : v);
          dst[((size_t)(bb * 16 + h) * 2048 + s) * 64 + dh] = f2bf(acc[mf][nf][r]);
        }
      }
  } else {
#pragma unroll
    for (int mf = 0; mf < 4; ++mf)
#pragma unroll
      for (int r = 0; r < 4; ++r) {
        int m = bm + wr * 64 + mf * 16 + l4 * 4 + r;
#pragma unroll
        for (int nf = 0; nf < 4; ++nf) {
          int n = bn + wc * 64 + nf * 16 + l15;
          outF[(size_t)m * N + n] = acc[mf][nf][r];
        }
      }
  }
}

// ---------------- causal flash attention ----------------
// Q,K,V: [BH=64][S=2048][64] bf16.  Out: [B][S][H][64] bf16 (= [B,S,1024]).
// Block: 256 thr = 4 waves; 128 q-rows/block (32/wave); KV tiles of 64.
__global__ __launch_bounds__(256) void attn_fwd(const short* __restrict__ Qb,
                                                const short* __restrict__ Kb,
                                                const short* __restrict__ Vb,
                                                short* __restrict__ Ob) {
  __shared__ short Kl[64 * 64];       // [krow][dh]
  __shared__ short Vt[64 * 64];       // [dh][krow]  (V transposed)
  __shared__ short Pl[4][32 * 64];    // per-wave P
  const int tid = threadIdx.x, lane = tid & 63, wv = tid >> 6;
  const int l15 = lane & 15, l4 = lane >> 4;
  const int qt = blockIdx.x, bh = blockIdx.y;
  const int b = bh >> 4, h = bh & 15;
  const int q0 = qt * 128;
  const size_t base = (size_t)bh * 2048 * 64;

  // Q fragments in registers: rows q0+wv*32+mf*16+l15, 8 dh elems at ks*32+l4*8
  short8 qa[2][2];
#pragma unroll
  for (int mf = 0; mf < 2; ++mf)
#pragma unroll
    for (int ks = 0; ks < 2; ++ks)
      qa[mf][ks] = *(const short8*)(Qb + base +
                                    (size_t)(q0 + wv * 32 + mf * 16 + l15) * 64 +
                                    ks * 32 + l4 * 8);

  f32x4 oacc[2][4] = {};
  float mrun[2][4], lrun[2][4];
#pragma unroll
  for (int mf = 0; mf < 2; ++mf)
#pragma unroll
    for (int j = 0; j < 4; ++j) { mrun[mf][j] = -1e30f; lrun[mf][j] = 0.f; }

  const int nt = 2 * qt + 2;  // KV cols 0 .. q0+127
  for (int t = 0; t < nt; ++t) {
    const int kv0 = t * 64;
    // stage K tile (64x64x2B = 8KB = 512 x 16B -> 2 iters)
#pragma unroll
    for (int i = 0; i < 2; ++i) {
      int c = i * 256 + tid;
      gload_lds16(Kb + base + (size_t)(kv0 + (c >> 3)) * 64 + (c & 7) * 8,
                  (char*)Kl + (size_t)c * 16);
    }
    // stage V^T (reg-staged transpose)
#pragma unroll
    for (int i = 0; i < 2; ++i) {
      int c = i * 256 + tid;
      int r = c >> 3, c0 = (c & 7) * 8;
      short8 vv = *(const short8*)(Vb + base + (size_t)(kv0 + r) * 64 + c0);
#pragma unroll
      for (int j = 0; j < 8; ++j) Vt[(c0 + j) * 64 + r] = vv[j];
    }
    __syncthreads();

    const bool diag = (t >= 2 * qt);
#pragma unroll
    for (int mf = 0; mf < 2; ++mf) {
      f32x4 sc[4] = {};
#pragma unroll
      for (int ks = 0; ks < 2; ++ks) {
        short8 kf[4];
#pragma unroll
        for (int nb = 0; nb < 4; ++nb)
          kf[nb] = *(const short8*)&Kl[(nb * 16 + l15) * 64 + ks * 32 + l4 * 8];
#pragma unroll
        for (int nb = 0; nb < 4; ++nb)
          sc[nb] = __builtin_amdgcn_mfma_f32_16x16x32_bf16(qa[mf][ks], kf[nb], sc[nb], 0, 0, 0);
      }
      const int rowb = q0 + wv * 32 + mf * 16 + l4 * 4;
      float sv[4][4];
#pragma unroll
      for (int r = 0; r < 4; ++r)
#pragma unroll
        for (int nb = 0; nb < 4; ++nb) {
          float s = sc[nb][r] * 0.125f;
          if (diag && (kv0 + nb * 16 + l15 > rowb + r)) s = -1e30f;
          sv[r][nb] = s;
        }
#pragma unroll
      for (int r = 0; r < 4; ++r) {
        float mx = fmaxf(fmaxf(sv[r][0], sv[r][1]), fmaxf(sv[r][2], sv[r][3]));
#pragma unroll
        for (int d = 1; d < 16; d <<= 1) mx = fmaxf(mx, __shfl_xor(mx, d));
        float mnew = fmaxf(mrun[mf][r], mx);
        float alpha = __expf(mrun[mf][r] - mnew);
        float ps = 0.f;
#pragma unroll
        for (int nb = 0; nb < 4; ++nb) {
          float p = __expf(sv[r][nb] - mnew);
          sv[r][nb] = p;
          ps += p;
        }
#pragma unroll
        for (int d = 1; d < 16; d <<= 1) ps += __shfl_xor(ps, d);
        mrun[mf][r] = mnew;
        lrun[mf][r] = lrun[mf][r] * alpha + ps;
#pragma unroll
        for (int u = 0; u < 4; ++u) oacc[mf][u][r] *= alpha;
#pragma unroll
        for (int nb = 0; nb < 4; ++nb)
          Pl[wv][(mf * 16 + l4 * 4 + r) * 64 + nb * 16 + l15] = f2bf(sv[r][nb]);
      }
    }
    // PV: O += P(32x64) * V(64x64)
#pragma unroll
    for (int mf = 0; mf < 2; ++mf)
#pragma unroll
      for (int ks = 0; ks < 2; ++ks) {
        short8 pa = *(const short8*)&Pl[wv][(mf * 16 + l15) * 64 + ks * 32 + l4 * 8];
#pragma unroll
        for (int u = 0; u < 4; ++u) {
          short8 vf = *(const short8*)&Vt[(u * 16 + l15) * 64 + ks * 32 + l4 * 8];
          oacc[mf][u] = __builtin_amdgcn_mfma_f32_16x16x32_bf16(pa, vf, oacc[mf][u], 0, 0, 0);
        }
      }
    __syncthreads();
  }

#pragma unroll
  for (int mf = 0; mf < 2; ++mf)
#pragma unroll
    for (int r = 0; r < 4; ++r) {
      int s = q0 + wv * 32 + mf * 16 + l4 * 4 + r;
      float inv = 1.f / lrun[mf][r];
#pragma unroll
      for (int u = 0; u < 4; ++u)
        Ob[(size_t)(b * 2048 + s) * 1024 + h * 64 + u * 16 + l15] =
            f2bf(oacc[mf][u][r] * inv);
    }
}

// ---------------- launch ----------------
extern "C" void kernel_launch(void* const* d_in, const int* in_sizes, int n_in,
                              void* d_out, int out_size, void* d_ws, size_t ws_size,
                              hipStream_t stream) {
  const float* x = (const float*)d_in[0];      // [4,2048,1024]
  const float* w_qkv = (const float*)d_in[1];  // [3072,1024]
  const float* w_out = (const float*)d_in[2];  // [1024,1024]
  float* out = (float*)d_out;                  // [4,2048,1024] fp32

  char* ws = (char*)d_ws;
  const size_t MB = 1024 * 1024;
  short* xb    = (short*)(ws + 0 * MB);    // 16 MB  [8192][1024]; dead after QKV GEMM
  short* wqkvb = (short*)(ws + 16 * MB);   // 6 MB   [3072][1024]
  short* woutb = (short*)(ws + 22 * MB);   // 2 MB   [1024][1024]
  short* qb    = (short*)(ws + 24 * MB);   // 16 MB  [64][2048][64]
  short* kb    = (short*)(ws + 40 * MB);   // 16 MB
  short* vb    = (short*)(ws + 56 * MB);   // 16 MB  (total 72 MB)
  short* ao    = xb;                       // reuse xb region for attn output

  cvt_bf16<<<4096, 256, 0, stream>>>(x, xb, 8192 * 1024 / 8);
  cvt_bf16<<<1536, 256, 0, stream>>>(w_qkv, wqkvb, 3072 * 1024 / 8);
  cvt_bf16<<<512, 256, 0, stream>>>(w_out, woutb, 1024 * 1024 / 8);

  // QKV projection: [8192,1024] x [3072,1024]^T -> scatter q/k/v
  gemm_bt<<<dim3(3072 / 128, 8192 / 128), 256, 0, stream>>>(
      xb, wqkvb, 1024, 0, qb, kb, vb, nullptr, 3072);

  // causal flash attention
  attn_fwd<<<dim3(2048 / 128, 64), 256, 0, stream>>>(qb, kb, vb, ao);

  // output projection: [8192,1024] x [1024,1024]^T -> fp32 out
  gemm_bt<<<dim3(1024 / 128, 8192 / 128), 256, 0, stream>>>(
      ao, woutb, 1024, 1, nullptr, nullptr, nullptr, out, 1024);
}

// Round 3
// 271.582 us; speedup vs baseline: 1.6971x; 1.6971x over previous
//
#include <hip/hip_runtime.h>
#include <stdint.h>

typedef __attribute__((ext_vector_type(8))) short short8;
typedef __attribute__((ext_vector_type(4))) float f32x4;

#define AS1 __attribute__((address_space(1)))
#define AS3 __attribute__((address_space(3)))

// XOR swizzle (16B-chunk granularity) for 64-short rows: spreads stride-128B
// row accesses across banks. Involution in the chunk index.
#define FSWZ(row) ((((row)) & 7) ^ (((row) >> 3) & 7))

__device__ __forceinline__ void gload_lds16(const void* g, void* l) {
  __builtin_amdgcn_global_load_lds((const AS1 void*)g, (AS3 void*)l, 16, 0, 0);
}

__device__ __forceinline__ short f2bf(float f) {
  uint32_t u = __float_as_uint(f);
  u += 0x7fffu + ((u >> 16) & 1u);
  return (short)(u >> 16);
}

// ---------------- fp32 -> bf16 conversion, 8 elems/thread ----------------
__global__ __launch_bounds__(256) void cvt_bf16(const float* __restrict__ in,
                                                short* __restrict__ out, int n8) {
  int i = blockIdx.x * 256 + threadIdx.x;
  if (i >= n8) return;
  const float4* p = (const float4*)(in + (size_t)i * 8);
  float4 a = p[0], b = p[1];
  short8 o;
  o[0] = f2bf(a.x); o[1] = f2bf(a.y); o[2] = f2bf(a.z); o[3] = f2bf(a.w);
  o[4] = f2bf(b.x); o[5] = f2bf(b.y); o[6] = f2bf(b.z); o[7] = f2bf(b.w);
  *(short8*)(out + (size_t)i * 8) = o;
}

// ---------------- GEMM: C[M,N] = A[M,K] * B[N,K]^T (both bf16, K%64==0) ----
__global__ __launch_bounds__(256) void gemm_bt(const short* __restrict__ A,
                                               const short* __restrict__ B,
                                               int K, int epi,
                                               short* __restrict__ q,
                                               short* __restrict__ k,
                                               short* __restrict__ v,
                                               float* __restrict__ outF, int N) {
  __shared__ short Al[128 * 64];
  __shared__ short Bl[128 * 64];
  const int tid = threadIdx.x;
  const int lane = tid & 63;
  const int wv = tid >> 6;
  const int wr = wv >> 1, wc = wv & 1;
  const int bm = blockIdx.y * 128, bn = blockIdx.x * 128;
  const int l15 = lane & 15, l4 = lane >> 4;

  f32x4 acc[4][4] = {};

  for (int kt = 0; kt < K; kt += 64) {
#pragma unroll
    for (int i = 0; i < 4; ++i) {
      int c = i * 256 + tid;
      int row = c >> 3, col = (c & 7) * 8;
      gload_lds16(A + (size_t)(bm + row) * K + kt + col, (char*)Al + (size_t)c * 16);
      gload_lds16(B + (size_t)(bn + row) * K + kt + col, (char*)Bl + (size_t)c * 16);
    }
    __syncthreads();
#pragma unroll
    for (int ks = 0; ks < 2; ++ks) {
      short8 af[4], bf[4];
#pragma unroll
      for (int mf = 0; mf < 4; ++mf)
        af[mf] = *(const short8*)&Al[(wr * 64 + mf * 16 + l15) * 64 + ks * 32 + l4 * 8];
#pragma unroll
      for (int nf = 0; nf < 4; ++nf)
        bf[nf] = *(const short8*)&Bl[(wc * 64 + nf * 16 + l15) * 64 + ks * 32 + l4 * 8];
#pragma unroll
      for (int mf = 0; mf < 4; ++mf)
#pragma unroll
        for (int nf = 0; nf < 4; ++nf)
          acc[mf][nf] =
              __builtin_amdgcn_mfma_f32_16x16x32_bf16(af[mf], bf[nf], acc[mf][nf], 0, 0, 0);
    }
    __syncthreads();
  }

  if (epi == 0) {
#pragma unroll
    for (int mf = 0; mf < 4; ++mf)
#pragma unroll
      for (int r = 0; r < 4; ++r) {
        int m = bm + wr * 64 + mf * 16 + l4 * 4 + r;
        int bb = m >> 11, s = m & 2047;
#pragma unroll
        for (int nf = 0; nf < 4; ++nf) {
          int n = bn + wc * 64 + nf * 16 + l15;
          int which = n >> 10, d = n & 1023, h = d >> 6, dh = d & 63;
          short* dst = (which == 0) ? q : ((which == 1) ? k : v);
          dst[((size_t)(bb * 16 + h) * 2048 + s) * 64 + dh] = f2bf(acc[mf][nf][r]);
        }
      }
  } else {
#pragma unroll
    for (int mf = 0; mf < 4; ++mf)
#pragma unroll
      for (int r = 0; r < 4; ++r) {
        int m = bm + wr * 64 + mf * 16 + l4 * 4 + r;
#pragma unroll
        for (int nf = 0; nf < 4; ++nf) {
          int n = bn + wc * 64 + nf * 16 + l15;
          outF[(size_t)m * N + n] = acc[mf][nf][r];
        }
      }
  }
}

// ---------------- causal flash attention ----------------
// Q,K,V: [BH=64][S=2048][64] bf16.  Out: [B][S][H][64] bf16 (= [B,S,1024]).
// Block: 256 thr = 4 waves; 128 q-rows/block (32/wave); KV tiles of 64.
// Grid: (bh=64, qt=16), qt reversed for heavy-first dispatch + CU balance.
// All LDS tiles XOR-swizzled (FSWZ) at 16B-chunk granularity.
__global__ __launch_bounds__(256) void attn_fwd(const short* __restrict__ Qb,
                                                const short* __restrict__ Kb,
                                                const short* __restrict__ Vb,
                                                short* __restrict__ Ob) {
  __shared__ short Kl[64 * 64];       // [krow][dh], swizzled, staged via gload_lds
  __shared__ short Vt[64 * 64];       // [dh][krow], swizzled, reg-transposed
  __shared__ short Pl[4][32 * 64];    // per-wave P, swizzled
  const int tid = threadIdx.x, lane = tid & 63, wv = tid >> 6;
  const int l15 = lane & 15, l4 = lane >> 4;
  const int bh = blockIdx.x;
  const int qt = (int)gridDim.y - 1 - (int)blockIdx.y;  // heavy blocks first
  const int b = bh >> 4, h = bh & 15;
  const int q0 = qt * 128;
  const size_t base = (size_t)bh * 2048 * 64;

  // Q fragments in registers
  short8 qa[2][2];
#pragma unroll
  for (int mf = 0; mf < 2; ++mf)
#pragma unroll
    for (int ks = 0; ks < 2; ++ks)
      qa[mf][ks] = *(const short8*)(Qb + base +
                                    (size_t)(q0 + wv * 32 + mf * 16 + l15) * 64 +
                                    ks * 32 + l4 * 8);

  f32x4 oacc[2][4] = {};
  float mrun[2][4], lrun[2][4];
#pragma unroll
  for (int mf = 0; mf < 2; ++mf)
#pragma unroll
    for (int j = 0; j < 4; ++j) { mrun[mf][j] = -1e30f; lrun[mf][j] = 0.f; }

  const int nt = 2 * qt + 2;
  for (int t = 0; t < nt; ++t) {
    const int kv0 = t * 64;
    // stage K tile: linear LDS dest + inverse-swizzled global source (rule #21)
#pragma unroll
    for (int i = 0; i < 2; ++i) {
      int c = i * 256 + tid;
      int row = c >> 3, j = c & 7;
      int jsrc = j ^ FSWZ(row);
      gload_lds16(Kb + base + (size_t)(kv0 + row) * 64 + jsrc * 8,
                  (char*)Kl + (size_t)c * 16);
    }
    // stage V^T: reg transpose, swizzled scalar writes (2-way max = free)
#pragma unroll
    for (int i = 0; i < 2; ++i) {
      int c = i * 256 + tid;
      int kr = c >> 3, c0 = (c & 7) * 8;
      short8 vv = *(const short8*)(Vb + base + (size_t)(kv0 + kr) * 64 + c0);
#pragma unroll
      for (int j = 0; j < 8; ++j) {
        int vr = c0 + j;  // dh row of V^T
        Vt[vr * 64 + (((kr >> 3) ^ FSWZ(vr)) * 8) + (kr & 7)] = vv[j];
      }
    }
    __syncthreads();

    const bool diag = (t >= 2 * qt);
#pragma unroll
    for (int mf = 0; mf < 2; ++mf) {
      f32x4 sc[4] = {};
#pragma unroll
      for (int ks = 0; ks < 2; ++ks) {
        short8 kf[4];
#pragma unroll
        for (int nb = 0; nb < 4; ++nb) {
          int row = nb * 16 + l15;
          kf[nb] = *(const short8*)&Kl[row * 64 + (((ks * 4 + l4) ^ FSWZ(row)) * 8)];
        }
#pragma unroll
        for (int nb = 0; nb < 4; ++nb)
          sc[nb] = __builtin_amdgcn_mfma_f32_16x16x32_bf16(qa[mf][ks], kf[nb], sc[nb], 0, 0, 0);
      }
      const int rowb = q0 + wv * 32 + mf * 16 + l4 * 4;
      float sv[4][4];
#pragma unroll
      for (int r = 0; r < 4; ++r)
#pragma unroll
        for (int nb = 0; nb < 4; ++nb) {
          float s = sc[nb][r] * 0.125f;
          if (diag && (kv0 + nb * 16 + l15 > rowb + r)) s = -1e30f;
          sv[r][nb] = s;
        }
#pragma unroll
      for (int r = 0; r < 4; ++r) {
        float mx = fmaxf(fmaxf(sv[r][0], sv[r][1]), fmaxf(sv[r][2], sv[r][3]));
#pragma unroll
        for (int d = 1; d < 16; d <<= 1) mx = fmaxf(mx, __shfl_xor(mx, d));
        float mnew = fmaxf(mrun[mf][r], mx);
        float alpha = __expf(mrun[mf][r] - mnew);
        float ps = 0.f;
#pragma unroll
        for (int nb = 0; nb < 4; ++nb) {
          float p = __expf(sv[r][nb] - mnew);
          sv[r][nb] = p;
          ps += p;
        }
#pragma unroll
        for (int d = 1; d < 16; d <<= 1) ps += __shfl_xor(ps, d);
        mrun[mf][r] = mnew;
        lrun[mf][r] = lrun[mf][r] * alpha + ps;
#pragma unroll
        for (int u = 0; u < 4; ++u) oacc[mf][u][r] *= alpha;
        {
          int prow = mf * 16 + l4 * 4 + r;
          int f = FSWZ(prow);
#pragma unroll
          for (int nb = 0; nb < 4; ++nb) {
            int col = nb * 16 + l15;
            Pl[wv][prow * 64 + (((col >> 3) ^ f) * 8) + (col & 7)] = f2bf(sv[r][nb]);
          }
        }
      }
    }
    // PV: O += P(32x64) * V(64x64)
#pragma unroll
    for (int mf = 0; mf < 2; ++mf)
#pragma unroll
      for (int ks = 0; ks < 2; ++ks) {
        int prow = mf * 16 + l15;
        short8 pa = *(const short8*)&Pl[wv][prow * 64 + (((ks * 4 + l4) ^ FSWZ(prow)) * 8)];
#pragma unroll
        for (int u = 0; u < 4; ++u) {
          int vr = u * 16 + l15;
          short8 vf = *(const short8*)&Vt[vr * 64 + (((ks * 4 + l4) ^ FSWZ(vr)) * 8)];
          oacc[mf][u] = __builtin_amdgcn_mfma_f32_16x16x32_bf16(pa, vf, oacc[mf][u], 0, 0, 0);
        }
      }
    __syncthreads();
  }

#pragma unroll
  for (int mf = 0; mf < 2; ++mf)
#pragma unroll
    for (int r = 0; r < 4; ++r) {
      int s = q0 + wv * 32 + mf * 16 + l4 * 4 + r;
      float inv = 1.f / lrun[mf][r];
#pragma unroll
      for (int u = 0; u < 4; ++u)
        Ob[(size_t)(b * 2048 + s) * 1024 + h * 64 + u * 16 + l15] =
            f2bf(oacc[mf][u][r] * inv);
    }
}

// ---------------- launch ----------------
extern "C" void kernel_launch(void* const* d_in, const int* in_sizes, int n_in,
                              void* d_out, int out_size, void* d_ws, size_t ws_size,
                              hipStream_t stream) {
  const float* x = (const float*)d_in[0];      // [4,2048,1024]
  const float* w_qkv = (const float*)d_in[1];  // [3072,1024]
  const float* w_out = (const float*)d_in[2];  // [1024,1024]
  float* out = (float*)d_out;                  // [4,2048,1024] fp32

  char* ws = (char*)d_ws;
  const size_t MB = 1024 * 1024;
  short* xb    = (short*)(ws + 0 * MB);    // 16 MB; dead after QKV GEMM
  short* wqkvb = (short*)(ws + 16 * MB);   // 6 MB
  short* woutb = (short*)(ws + 22 * MB);   // 2 MB
  short* qb    = (short*)(ws + 24 * MB);   // 16 MB  [64][2048][64]
  short* kb    = (short*)(ws + 40 * MB);   // 16 MB
  short* vb    = (short*)(ws + 56 * MB);   // 16 MB  (total 72 MB)
  short* ao    = xb;                       // reuse xb for attn output

  cvt_bf16<<<4096, 256, 0, stream>>>(x, xb, 8192 * 1024 / 8);
  cvt_bf16<<<1536, 256, 0, stream>>>(w_qkv, wqkvb, 3072 * 1024 / 8);
  cvt_bf16<<<512, 256, 0, stream>>>(w_out, woutb, 1024 * 1024 / 8);

  gemm_bt<<<dim3(3072 / 128, 8192 / 128), 256, 0, stream>>>(
      xb, wqkvb, 1024, 0, qb, kb, vb, nullptr, 3072);

  attn_fwd<<<dim3(64, 16), 256, 0, stream>>>(qb, kb, vb, ao);

  gemm_bt<<<dim3(1024 / 128, 8192 / 128), 256, 0, stream>>>(
      ao, woutb, 1024, 1, nullptr, nullptr, nullptr, out, 1024);
}

// Round 4
// 233.000 us; speedup vs baseline: 1.9781x; 1.1656x over previous
//
#include <hip/hip_runtime.h>
#include <stdint.h>

typedef __attribute__((ext_vector_type(8))) short short8;
typedef __attribute__((ext_vector_type(4))) float f32x4;
typedef __attribute__((ext_vector_type(16))) float f32x16;
typedef __attribute__((ext_vector_type(4))) unsigned int u32x4;

#define AS1 __attribute__((address_space(1)))
#define AS3 __attribute__((address_space(3)))

// XOR swizzle (16B-chunk granularity) for 64-short rows.
#define FSWZ(row) ((((row)) & 7) ^ (((row) >> 3) & 7))

__device__ __forceinline__ void gload_lds16(const void* g, void* l) {
  __builtin_amdgcn_global_load_lds((const AS1 void*)g, (AS3 void*)l, 16, 0, 0);
}

__device__ __forceinline__ short f2bf(float f) {
  uint32_t u = __float_as_uint(f);
  u += 0x7fffu + ((u >> 16) & 1u);
  return (short)(u >> 16);
}

__device__ __forceinline__ unsigned int pk2bf(float lo, float hi) {
  return (unsigned int)(unsigned short)f2bf(lo) |
         ((unsigned int)(unsigned short)f2bf(hi) << 16);
}

// ---------------- fp32 -> bf16 conversion ----------------
__global__ __launch_bounds__(256) void cvt_bf16(const float* __restrict__ in,
                                                short* __restrict__ out, int n8) {
  int i = blockIdx.x * 256 + threadIdx.x;
  if (i >= n8) return;
  const float4* p = (const float4*)(in + (size_t)i * 8);
  float4 a = p[0], b = p[1];
  short8 o;
  o[0] = f2bf(a.x); o[1] = f2bf(a.y); o[2] = f2bf(a.z); o[3] = f2bf(a.w);
  o[4] = f2bf(b.x); o[5] = f2bf(b.y); o[6] = f2bf(b.z); o[7] = f2bf(b.w);
  *(short8*)(out + (size_t)i * 8) = o;
}

// ---------------- GEMM: C[M,N] = A[M,K] * B[N,K]^T ----------------
__global__ __launch_bounds__(256) void gemm_bt(const short* __restrict__ A,
                                               const short* __restrict__ B,
                                               int K, int epi,
                                               short* __restrict__ q,
                                               short* __restrict__ k,
                                               short* __restrict__ v,
                                               float* __restrict__ outF, int N) {
  __shared__ short Al[128 * 64];
  __shared__ short Bl[128 * 64];
  const int tid = threadIdx.x;
  const int lane = tid & 63;
  const int wv = tid >> 6;
  const int wr = wv >> 1, wc = wv & 1;
  const int bm = blockIdx.y * 128, bn = blockIdx.x * 128;
  const int l15 = lane & 15, l4 = lane >> 4;

  f32x4 acc[4][4] = {};

  for (int kt = 0; kt < K; kt += 64) {
#pragma unroll
    for (int i = 0; i < 4; ++i) {
      int c = i * 256 + tid;
      int row = c >> 3, col = (c & 7) * 8;
      gload_lds16(A + (size_t)(bm + row) * K + kt + col, (char*)Al + (size_t)c * 16);
      gload_lds16(B + (size_t)(bn + row) * K + kt + col, (char*)Bl + (size_t)c * 16);
    }
    __syncthreads();
#pragma unroll
    for (int ks = 0; ks < 2; ++ks) {
      short8 af[4], bf[4];
#pragma unroll
      for (int mf = 0; mf < 4; ++mf)
        af[mf] = *(const short8*)&Al[(wr * 64 + mf * 16 + l15) * 64 + ks * 32 + l4 * 8];
#pragma unroll
      for (int nf = 0; nf < 4; ++nf)
        bf[nf] = *(const short8*)&Bl[(wc * 64 + nf * 16 + l15) * 64 + ks * 32 + l4 * 8];
#pragma unroll
      for (int mf = 0; mf < 4; ++mf)
#pragma unroll
        for (int nf = 0; nf < 4; ++nf)
          acc[mf][nf] =
              __builtin_amdgcn_mfma_f32_16x16x32_bf16(af[mf], bf[nf], acc[mf][nf], 0, 0, 0);
    }
    __syncthreads();
  }

  if (epi == 0) {
#pragma unroll
    for (int mf = 0; mf < 4; ++mf)
#pragma unroll
      for (int r = 0; r < 4; ++r) {
        int m = bm + wr * 64 + mf * 16 + l4 * 4 + r;
        int bb = m >> 11, s = m & 2047;
#pragma unroll
        for (int nf = 0; nf < 4; ++nf) {
          int n = bn + wc * 64 + nf * 16 + l15;
          int which = n >> 10, d = n & 1023, h = d >> 6, dh = d & 63;
          short* dst = (which == 0) ? q : ((which == 1) ? k : v);
          dst[((size_t)(bb * 16 + h) * 2048 + s) * 64 + dh] = f2bf(acc[mf][nf][r]);
        }
      }
  } else {
#pragma unroll
    for (int mf = 0; mf < 4; ++mf)
#pragma unroll
      for (int r = 0; r < 4; ++r) {
        int m = bm + wr * 64 + mf * 16 + l4 * 4 + r;
#pragma unroll
        for (int nf = 0; nf < 4; ++nf) {
          int n = bn + wc * 64 + nf * 16 + l15;
          outF[(size_t)m * N + n] = acc[mf][nf][r];
        }
      }
  }
}

// ---------------- causal flash attention, 32x32 swapped structure ---------
// Q,K,V: [BH=64][S=2048][64] bf16.  Out: [B][S][H][64] bf16.
// 4 waves x 32 q-rows = 128 q/block. KV tiles of 64.
// Swapped QK^T: S^T = mfma(Kfrag, Qfrag) -> lane owns q-row = lane&31.
// Swapped PV:   O^T = mfma(V^T frag, P^T frag) -> alpha/l lane-local.
// 32x32x16 layouts: C col=lane&31, row=(r&3)+8*(r>>2)+4*(lane>>5);
//                   A/B frag: row/col=lane&31, k=(lane>>5)*8+e.
__global__ __launch_bounds__(256) void attn_fwd(const short* __restrict__ Qb,
                                                const short* __restrict__ Kb,
                                                const short* __restrict__ Vb,
                                                short* __restrict__ Ob) {
  __shared__ short Kl[64 * 64];  // [k][d], swizzled via pre-swizzled gload src
  __shared__ short Vt[64 * 64];  // [d][k], swizzled, reg-transposed
  const int tid = threadIdx.x, lane = tid & 63, wv = tid >> 6;
  const int l31 = lane & 31, l32 = lane >> 5;
  const int bh = blockIdx.x;
  const int qt = (int)gridDim.y - 1 - (int)blockIdx.y;  // heavy-first
  const int b = bh >> 4, h = bh & 15;
  const int q0 = qt * 128;
  const size_t base = (size_t)bh * 2048 * 64;
  const int qw0 = q0 + wv * 32;  // wave's first q-row
  const int qg = qw0 + l31;      // this lane's q-row

  // Q as B-fragments: qf[dk] covers d = dk*16 + l32*8 + e
  short8 qf[4];
#pragma unroll
  for (int dk = 0; dk < 4; ++dk)
    qf[dk] = *(const short8*)(Qb + base + (size_t)qg * 64 + dk * 16 + l32 * 8);

  f32x16 oacc[2] = {};  // O^T tiles: row d = dt*32 + rowpat, col q = l31
  float mrun = -1e30f, lrun = 0.f;
  const float SCL = 0.18033688f;  // 0.125 * log2(e)  (log2-domain softmax)

  const int nt = 2 * qt + 2;
  for (int t = 0; t < nt; ++t) {
    const int kv0 = t * 64;
    // stage K: linear LDS dest + inverse-swizzled global source
#pragma unroll
    for (int i = 0; i < 2; ++i) {
      int c = i * 256 + tid;
      int row = c >> 3, j = c & 7;
      int jsrc = j ^ FSWZ(row);
      gload_lds16(Kb + base + (size_t)(kv0 + row) * 64 + jsrc * 8,
                  (char*)Kl + (size_t)c * 16);
    }
    // stage V^T: reg transpose, swizzled scalar writes
#pragma unroll
    for (int i = 0; i < 2; ++i) {
      int c = i * 256 + tid;
      int kr = c >> 3, c0 = (c & 7) * 8;
      short8 vv = *(const short8*)(Vb + base + (size_t)(kv0 + kr) * 64 + c0);
#pragma unroll
      for (int j = 0; j < 8; ++j) {
        int vr = c0 + j;
        Vt[vr * 64 + (((kr >> 3) ^ FSWZ(vr)) * 8) + (kr & 7)] = vv[j];
      }
    }
    __syncthreads();

    if (kv0 <= qw0 + 31) {  // wave has rows reaching this tile
      // ---- QK^T (swapped): sc[kb] = S^T tile [k=kb*32.. x q] ----
      f32x16 sc[2] = {};
#pragma unroll
      for (int dk = 0; dk < 4; ++dk) {
#pragma unroll
        for (int kb = 0; kb < 2; ++kb) {
          int row = kb * 32 + l31;
          short8 kf = *(const short8*)&Kl[row * 64 + (((dk * 2 + l32) ^ FSWZ(row)) * 8)];
          sc[kb] = __builtin_amdgcn_mfma_f32_32x32x16_bf16(kf, qf[dk], sc[kb], 0, 0, 0);
        }
      }
      // ---- softmax (lane owns q-row = l31; k spread over regs + l32) ----
      const bool diag = (kv0 + 63 > qw0);
      float p[2][16];
#pragma unroll
      for (int kb = 0; kb < 2; ++kb)
#pragma unroll
        for (int r = 0; r < 16; ++r) {
          float s = sc[kb][r] * SCL;
          if (diag) {
            int kgl = kv0 + kb * 32 + (r & 3) + 8 * (r >> 2) + 4 * l32;
            if (kgl > qg) s = -1e30f;
          }
          p[kb][r] = s;
        }
      float mx = -1e30f;
#pragma unroll
      for (int kb = 0; kb < 2; ++kb)
#pragma unroll
        for (int r = 0; r < 16; ++r) mx = fmaxf(mx, p[kb][r]);
      mx = fmaxf(mx, __shfl_xor(mx, 32));
      float mnew = fmaxf(mrun, mx);
      float alpha = exp2f(mrun - mnew);
      float ls = 0.f;
#pragma unroll
      for (int kb = 0; kb < 2; ++kb)
#pragma unroll
        for (int r = 0; r < 16; ++r) {
          float e = exp2f(p[kb][r] - mnew);
          p[kb][r] = e;
          ls += e;
        }
      ls += __shfl_xor(ls, 32);
      lrun = lrun * alpha + ls;
      mrun = mnew;
#pragma unroll
      for (int dt = 0; dt < 2; ++dt)
#pragma unroll
        for (int r = 0; r < 16; ++r) oacc[dt][r] *= alpha;

      // ---- pack P to bf16 pairs; W[kb][g][u] = k0 = kb*32+8g+4*l32+2u ----
      unsigned int W[2][4][2];
#pragma unroll
      for (int kb = 0; kb < 2; ++kb)
#pragma unroll
        for (int g = 0; g < 4; ++g)
#pragma unroll
          for (int u = 0; u < 2; ++u)
            W[kb][g][u] = pk2bf(p[kb][g * 4 + 2 * u], p[kb][g * 4 + 2 * u + 1]);

      // ---- redistribute into PV B-fragments (P^T frag: col=q=l31,
      //      k = kblk*16 + l32*8 + e). dword dd: k0 = kblk*16+l32*8+2dd;
      //      holder: half dd>>1, reg g = 2*(kblk&1)+l32_target, u = dd&1. ----
      u32x4 pf[4];
#pragma unroll
      for (int kblk = 0; kblk < 4; ++kblk) {
        const int kbh = kblk >> 1;
#pragma unroll
        for (int u = 0; u < 2; ++u) {
          unsigned int A = W[kbh][2 * (kblk & 1)][u];
          unsigned int B = W[kbh][2 * (kblk & 1) + 1][u];
          unsigned int own = l32 ? B : A;
          unsigned int snd = l32 ? A : B;
          unsigned int rcv = (unsigned int)__shfl_xor((int)snd, 32);
          pf[kblk][0 + u] = l32 ? rcv : own;  // dd = 0,1 (holder half 0)
          pf[kblk][2 + u] = l32 ? own : rcv;  // dd = 2,3 (holder half 1)
        }
      }

      // ---- PV (swapped): oacc[dt] += V^T[dt] x P^T ----
#pragma unroll
      for (int dt = 0; dt < 2; ++dt)
#pragma unroll
        for (int kblk = 0; kblk < 4; ++kblk) {
          int row = dt * 32 + l31;
          short8 vf = *(const short8*)&Vt[row * 64 + (((kblk * 2 + l32) ^ FSWZ(row)) * 8)];
          oacc[dt] = __builtin_amdgcn_mfma_f32_32x32x16_bf16(
              vf, __builtin_bit_cast(short8, pf[kblk]), oacc[dt], 0, 0, 0);
        }
    }
    __syncthreads();
  }

  // ---- epilogue: O^T regs -> Ob[b][s][h*64+d]; inv lane-local ----
  float inv = 1.f / lrun;
#pragma unroll
  for (int dt = 0; dt < 2; ++dt)
#pragma unroll
    for (int r = 0; r < 16; ++r) {
      int d = dt * 32 + (r & 3) + 8 * (r >> 2) + 4 * l32;
      Ob[(size_t)(b * 2048 + qg) * 1024 + h * 64 + d] = f2bf(oacc[dt][r] * inv);
    }
}

// ---------------- launch ----------------
extern "C" void kernel_launch(void* const* d_in, const int* in_sizes, int n_in,
                              void* d_out, int out_size, void* d_ws, size_t ws_size,
                              hipStream_t stream) {
  const float* x = (const float*)d_in[0];      // [4,2048,1024]
  const float* w_qkv = (const float*)d_in[1];  // [3072,1024]
  const float* w_out = (const float*)d_in[2];  // [1024,1024]
  float* out = (float*)d_out;                  // [4,2048,1024] fp32

  char* ws = (char*)d_ws;
  const size_t MB = 1024 * 1024;
  short* xb    = (short*)(ws + 0 * MB);    // 16 MB; dead after QKV GEMM
  short* wqkvb = (short*)(ws + 16 * MB);   // 6 MB
  short* woutb = (short*)(ws + 22 * MB);   // 2 MB
  short* qb    = (short*)(ws + 24 * MB);   // 16 MB  [64][2048][64]
  short* kb    = (short*)(ws + 40 * MB);   // 16 MB
  short* vb    = (short*)(ws + 56 * MB);   // 16 MB  (total 72 MB)
  short* ao    = xb;                       // reuse xb for attn output

  cvt_bf16<<<4096, 256, 0, stream>>>(x, xb, 8192 * 1024 / 8);
  cvt_bf16<<<1536, 256, 0, stream>>>(w_qkv, wqkvb, 3072 * 1024 / 8);
  cvt_bf16<<<512, 256, 0, stream>>>(w_out, woutb, 1024 * 1024 / 8);

  gemm_bt<<<dim3(3072 / 128, 8192 / 128), 256, 0, stream>>>(
      xb, wqkvb, 1024, 0, qb, kb, vb, nullptr, 3072);

  attn_fwd<<<dim3(64, 16), 256, 0, stream>>>(qb, kb, vb, ao);

  gemm_bt<<<dim3(1024 / 128, 8192 / 128), 256, 0, stream>>>(
      ao, woutb, 1024, 1, nullptr, nullptr, nullptr, out, 1024);
}

// Round 5
// 223.762 us; speedup vs baseline: 2.0597x; 1.0413x over previous
//
#include <hip/hip_runtime.h>
#include <stdint.h>

typedef __attribute__((ext_vector_type(8))) short short8;
typedef __attribute__((ext_vector_type(4))) float f32x4;
typedef __attribute__((ext_vector_type(16))) float f32x16;
typedef __attribute__((ext_vector_type(4))) unsigned int u32x4;

#define AS1 __attribute__((address_space(1)))
#define AS3 __attribute__((address_space(3)))

// XOR swizzle (16B-chunk granularity) for 64-short rows.
#define FSWZ(row) ((((row)) & 7) ^ (((row) >> 3) & 7))

// 0.125 * log2(e): folded into K at GEMM epilogue; softmax in log2 domain.
#define KSCL 0.18033688f

__device__ __forceinline__ void gload_lds16(const void* g, void* l) {
  __builtin_amdgcn_global_load_lds((const AS1 void*)g, (AS3 void*)l, 16, 0, 0);
}

__device__ __forceinline__ short f2bf(float f) {
  uint32_t u = __float_as_uint(f);
  u += 0x7fffu + ((u >> 16) & 1u);
  return (short)(u >> 16);
}

__device__ __forceinline__ unsigned int cvtpk(float lo, float hi) {
  unsigned int r;
  asm("v_cvt_pk_bf16_f32 %0, %1, %2" : "=v"(r) : "v"(lo), "v"(hi));
  return r;
}

// ---------------- fp32 -> bf16 conversion ----------------
__global__ __launch_bounds__(256) void cvt_bf16(const float* __restrict__ in,
                                                short* __restrict__ out, int n8) {
  int i = blockIdx.x * 256 + threadIdx.x;
  if (i >= n8) return;
  const float4* p = (const float4*)(in + (size_t)i * 8);
  float4 a = p[0], b = p[1];
  short8 o;
  o[0] = f2bf(a.x); o[1] = f2bf(a.y); o[2] = f2bf(a.z); o[3] = f2bf(a.w);
  o[4] = f2bf(b.x); o[5] = f2bf(b.y); o[6] = f2bf(b.z); o[7] = f2bf(b.w);
  *(short8*)(out + (size_t)i * 8) = o;
}

// ---------------- GEMM: C[M,N] = A[M,K] * B[N,K]^T ----------------
__global__ __launch_bounds__(256) void gemm_bt(const short* __restrict__ A,
                                               const short* __restrict__ B,
                                               int K, int epi,
                                               short* __restrict__ q,
                                               short* __restrict__ k,
                                               short* __restrict__ v,
                                               float* __restrict__ outF, int N) {
  __shared__ short Al[128 * 64];
  __shared__ short Bl[128 * 64];
  const int tid = threadIdx.x;
  const int lane = tid & 63;
  const int wv = tid >> 6;
  const int wr = wv >> 1, wc = wv & 1;
  const int bm = blockIdx.y * 128, bn = blockIdx.x * 128;
  const int l15 = lane & 15, l4 = lane >> 4;

  f32x4 acc[4][4] = {};

  for (int kt = 0; kt < K; kt += 64) {
#pragma unroll
    for (int i = 0; i < 4; ++i) {
      int c = i * 256 + tid;
      int row = c >> 3, col = (c & 7) * 8;
      gload_lds16(A + (size_t)(bm + row) * K + kt + col, (char*)Al + (size_t)c * 16);
      gload_lds16(B + (size_t)(bn + row) * K + kt + col, (char*)Bl + (size_t)c * 16);
    }
    __syncthreads();
#pragma unroll
    for (int ks = 0; ks < 2; ++ks) {
      short8 af[4], bf[4];
#pragma unroll
      for (int mf = 0; mf < 4; ++mf)
        af[mf] = *(const short8*)&Al[(wr * 64 + mf * 16 + l15) * 64 + ks * 32 + l4 * 8];
#pragma unroll
      for (int nf = 0; nf < 4; ++nf)
        bf[nf] = *(const short8*)&Bl[(wc * 64 + nf * 16 + l15) * 64 + ks * 32 + l4 * 8];
#pragma unroll
      for (int mf = 0; mf < 4; ++mf)
#pragma unroll
        for (int nf = 0; nf < 4; ++nf)
          acc[mf][nf] =
              __builtin_amdgcn_mfma_f32_16x16x32_bf16(af[mf], bf[nf], acc[mf][nf], 0, 0, 0);
    }
    __syncthreads();
  }

  if (epi == 0) {
#pragma unroll
    for (int mf = 0; mf < 4; ++mf)
#pragma unroll
      for (int r = 0; r < 4; ++r) {
        int m = bm + wr * 64 + mf * 16 + l4 * 4 + r;
        int bb = m >> 11, s = m & 2047;
#pragma unroll
        for (int nf = 0; nf < 4; ++nf) {
          int n = bn + wc * 64 + nf * 16 + l15;
          int which = n >> 10, d = n & 1023, h = d >> 6, dh = d & 63;
          short* dst = (which == 0) ? q : ((which == 1) ? k : v);
          float val = acc[mf][nf][r];
          if (which == 1) val *= KSCL;  // fold softmax scale into K
          dst[((size_t)(bb * 16 + h) * 2048 + s) * 64 + dh] = f2bf(val);
        }
      }
  } else {
#pragma unroll
    for (int mf = 0; mf < 4; ++mf)
#pragma unroll
      for (int r = 0; r < 4; ++r) {
        int m = bm + wr * 64 + mf * 16 + l4 * 4 + r;
#pragma unroll
        for (int nf = 0; nf < 4; ++nf) {
          int n = bn + wc * 64 + nf * 16 + l15;
          outF[(size_t)m * N + n] = acc[mf][nf][r];
        }
      }
  }
}

// ---------------- causal flash attention, pipelined 32x32 swapped ---------
// Q,K,V: [BH=64][S=2048][64] bf16 (K pre-scaled by 0.125*log2e).
// Out: [B][S][H][64] bf16.
// Grid (bh=64, p=8): block does q-tiles {p, 15-p} = 34 tile-units uniform.
// Double-buffered K/V LDS; 1 barrier/tile; next-tile loads fly over compute.
__global__ __launch_bounds__(256) void attn_fwd(const short* __restrict__ Qb,
                                                const short* __restrict__ Kb,
                                                const short* __restrict__ Vb,
                                                short* __restrict__ Ob) {
  __shared__ short Kl[2][64 * 64];  // [k][d], swizzled via pre-swizzled src
  __shared__ short Vt[2][64 * 64];  // [d][k], swizzled, reg-transposed
  const int tid = threadIdx.x, lane = tid & 63, wv = tid >> 6;
  const int l31 = lane & 31, l32 = lane >> 5;
  const int bh = blockIdx.x;
  const int pr = blockIdx.y;
  const int b = bh >> 4, h = bh & 15;
  const size_t base = (size_t)bh * 2048 * 64;

  short8 vv[2];  // in-flight V tile regs

  for (int hf = 0; hf < 2; ++hf) {
    const int qt = hf ? (15 - pr) : pr;
    const int q0 = qt * 128;
    const int qw0 = q0 + wv * 32;
    const int qg = qw0 + l31;

    // Q as B-fragments: qf[dk] covers d = dk*16 + l32*8 + e
    short8 qf[4];
#pragma unroll
    for (int dk = 0; dk < 4; ++dk)
      qf[dk] = *(const short8*)(Qb + base + (size_t)qg * 64 + dk * 16 + l32 * 8);

    f32x16 oacc[2] = {};
    float mrun = -1e30f, lrun = 0.f;

    const int nt = 2 * qt + 2;
    // prologue: issue tile 0 loads
#pragma unroll
    for (int i = 0; i < 2; ++i) {
      int c = i * 256 + tid;
      int row = c >> 3, j = c & 7;
      gload_lds16(Kb + base + (size_t)row * 64 + (j ^ FSWZ(row)) * 8,
                  (char*)Kl[0] + (size_t)c * 16);
      vv[i] = *(const short8*)(Vb + base + (size_t)(c >> 3) * 64 + (c & 7) * 8);
    }

    for (int t = 0; t < nt; ++t) {
      const int cur = t & 1;
      const int kv0 = t * 64;
      // write V^T for tile t (waits vv), swizzled scalar writes
#pragma unroll
      for (int i = 0; i < 2; ++i) {
        int c = i * 256 + tid;
        int kr = c >> 3, c0 = (c & 7) * 8;
#pragma unroll
        for (int j = 0; j < 8; ++j) {
          int vr = c0 + j;
          Vt[cur][vr * 64 + (((kr >> 3) ^ FSWZ(vr)) * 8) + (kr & 7)] = vv[i][j];
        }
      }
      __syncthreads();  // buf[cur] complete (K gloads drained, V writes visible)

      if (t + 1 < nt) {  // issue next tile's loads; fly over compute
        const int kv1 = kv0 + 64;
#pragma unroll
        for (int i = 0; i < 2; ++i) {
          int c = i * 256 + tid;
          int row = c >> 3, j = c & 7;
          gload_lds16(Kb + base + (size_t)(kv1 + row) * 64 + (j ^ FSWZ(row)) * 8,
                      (char*)Kl[cur ^ 1] + (size_t)c * 16);
          vv[i] = *(const short8*)(Vb + base + (size_t)(kv1 + (c >> 3)) * 64 + (c & 7) * 8);
        }
      }

      if (kv0 <= qw0 + 31) {
        // ---- QK^T (swapped): sc[kb] = S^T tile ----
        f32x16 sc[2] = {};
        __builtin_amdgcn_s_setprio(1);
#pragma unroll
        for (int dk = 0; dk < 4; ++dk)
#pragma unroll
          for (int kb = 0; kb < 2; ++kb) {
            int row = kb * 32 + l31;
            short8 kf =
                *(const short8*)&Kl[cur][row * 64 + (((dk * 2 + l32) ^ FSWZ(row)) * 8)];
            sc[kb] = __builtin_amdgcn_mfma_f32_32x32x16_bf16(kf, qf[dk], sc[kb], 0, 0, 0);
          }
        __builtin_amdgcn_s_setprio(0);

        // ---- softmax (K pre-scaled; log2 domain) ----
        const bool diag = (kv0 + 63 > qw0);
        float pp[2][16];
#pragma unroll
        for (int kb = 0; kb < 2; ++kb)
#pragma unroll
          for (int r = 0; r < 16; ++r) {
            float s = sc[kb][r];
            if (diag) {
              int kgl = kv0 + kb * 32 + (r & 3) + 8 * (r >> 2) + 4 * l32;
              if (kgl > qg) s = -1e30f;
            }
            pp[kb][r] = s;
          }
        float mx = -1e30f;
#pragma unroll
        for (int kb = 0; kb < 2; ++kb)
#pragma unroll
          for (int r = 0; r < 16; ++r) mx = fmaxf(mx, pp[kb][r]);
        mx = fmaxf(mx, __shfl_xor(mx, 32));
        // defer-max: rescale only when max grew past THR (=8*log2e)
        if (!__all(mx - mrun <= 11.5416f)) {
          float mnew = fmaxf(mrun, mx);
          float alpha = exp2f(mrun - mnew);
          lrun *= alpha;
#pragma unroll
          for (int dt = 0; dt < 2; ++dt)
#pragma unroll
            for (int r = 0; r < 16; ++r) oacc[dt][r] *= alpha;
          mrun = mnew;
        }
        float ls = 0.f;
#pragma unroll
        for (int kb = 0; kb < 2; ++kb)
#pragma unroll
          for (int r = 0; r < 16; ++r) {
            float e = exp2f(pp[kb][r] - mrun);
            pp[kb][r] = e;
            ls += e;
          }
        ls += __shfl_xor(ls, 32);
        lrun += ls;

        // ---- pack P pairs: W[kb][g][u] covers k0 = kb*32+8g+4*l32+2u ----
        unsigned int W[2][4][2];
#pragma unroll
        for (int kb = 0; kb < 2; ++kb)
#pragma unroll
          for (int g = 0; g < 4; ++g)
#pragma unroll
            for (int u = 0; u < 2; ++u)
              W[kb][g][u] = cvtpk(pp[kb][g * 4 + 2 * u], pp[kb][g * 4 + 2 * u + 1]);

        // ---- redistribute into PV B-fragments ----
        u32x4 pf[4];
#pragma unroll
        for (int kblk = 0; kblk < 4; ++kblk) {
          const int kbh = kblk >> 1;
#pragma unroll
          for (int u = 0; u < 2; ++u) {
            unsigned int A = W[kbh][2 * (kblk & 1)][u];
            unsigned int B = W[kbh][2 * (kblk & 1) + 1][u];
            unsigned int own = l32 ? B : A;
            unsigned int snd = l32 ? A : B;
            unsigned int rcv = (unsigned int)__shfl_xor((int)snd, 32);
            pf[kblk][0 + u] = l32 ? rcv : own;
            pf[kblk][2 + u] = l32 ? own : rcv;
          }
        }

        // ---- PV (swapped): oacc[dt] += V^T[dt] x P^T ----
        __builtin_amdgcn_s_setprio(1);
#pragma unroll
        for (int dt = 0; dt < 2; ++dt)
#pragma unroll
          for (int kblk = 0; kblk < 4; ++kblk) {
            int row = dt * 32 + l31;
            short8 vf =
                *(const short8*)&Vt[cur][row * 64 + (((kblk * 2 + l32) ^ FSWZ(row)) * 8)];
            oacc[dt] = __builtin_amdgcn_mfma_f32_32x32x16_bf16(
                vf, __builtin_bit_cast(short8, pf[kblk]), oacc[dt], 0, 0, 0);
          }
        __builtin_amdgcn_s_setprio(0);
      }
    }
    __syncthreads();  // protect buffers before next half / finish reads

    // ---- epilogue ----
    float inv = 1.f / lrun;
#pragma unroll
    for (int dt = 0; dt < 2; ++dt)
#pragma unroll
      for (int r = 0; r < 16; ++r) {
        int d = dt * 32 + (r & 3) + 8 * (r >> 2) + 4 * l32;
        Ob[(size_t)(b * 2048 + qg) * 1024 + h * 64 + d] = f2bf(oacc[dt][r] * inv);
      }
  }
}

// ---------------- launch ----------------
extern "C" void kernel_launch(void* const* d_in, const int* in_sizes, int n_in,
                              void* d_out, int out_size, void* d_ws, size_t ws_size,
                              hipStream_t stream) {
  const float* x = (const float*)d_in[0];      // [4,2048,1024]
  const float* w_qkv = (const float*)d_in[1];  // [3072,1024]
  const float* w_out = (const float*)d_in[2];  // [1024,1024]
  float* out = (float*)d_out;                  // [4,2048,1024] fp32

  char* ws = (char*)d_ws;
  const size_t MB = 1024 * 1024;
  short* xb    = (short*)(ws + 0 * MB);    // 16 MB; dead after QKV GEMM
  short* wqkvb = (short*)(ws + 16 * MB);   // 6 MB
  short* woutb = (short*)(ws + 22 * MB);   // 2 MB
  short* qb    = (short*)(ws + 24 * MB);   // 16 MB  [64][2048][64]
  short* kb    = (short*)(ws + 40 * MB);   // 16 MB (pre-scaled by KSCL)
  short* vb    = (short*)(ws + 56 * MB);   // 16 MB  (total 72 MB)
  short* ao    = xb;                       // reuse xb for attn output

  cvt_bf16<<<4096, 256, 0, stream>>>(x, xb, 8192 * 1024 / 8);
  cvt_bf16<<<1536, 256, 0, stream>>>(w_qkv, wqkvb, 3072 * 1024 / 8);
  cvt_bf16<<<512, 256, 0, stream>>>(w_out, woutb, 1024 * 1024 / 8);

  gemm_bt<<<dim3(3072 / 128, 8192 / 128), 256, 0, stream>>>(
      xb, wqkvb, 1024, 0, qb, kb, vb, nullptr, 3072);

  attn_fwd<<<dim3(64, 8), 256, 0, stream>>>(qb, kb, vb, ao);

  gemm_bt<<<dim3(1024 / 128, 8192 / 128), 256, 0, stream>>>(
      ao, woutb, 1024, 1, nullptr, nullptr, nullptr, out, 1024);
}